// Round 6
// baseline (160.869 us; speedup 1.0000x reference)
//
#include <hip/hip_runtime.h>
#include <hip/hip_bf16.h>

// LSTM cell fused kernel for MI355X (gfx950).
// B=65536, H=256. Packed GEMM [B,256]x[256,1024] bf16 MFMA + fused gates.
// R6: occupancy push — wave tile 32r x 16j x 4 gates (acc=32 regs), 512-thr
//     blocks (8 waves) on 32r x 128j, cell/bias direct per-lane loads issued
//     pre-barrier, LDS = combine tile only (16 KB). Target 3 blocks/CU.

typedef __attribute__((ext_vector_type(8))) short short8;   // 8 bf16
typedef __attribute__((ext_vector_type(4))) float f32x4;

static constexpr int Bsz   = 65536;
static constexpr int Hdim  = 256;
static constexpr int TROWS = 32;
static constexpr int NBLK  = (Bsz / TROWS) * 2;   // 4096 blocks (2 j-halves)

// float -> bf16 bits, round-to-nearest-even
__device__ __forceinline__ short f2bf(float f) {
    unsigned u = __float_as_uint(f);
    return (short)((u + 0x7FFFu + ((u >> 16) & 1u)) >> 16);
}
__device__ __forceinline__ float sigm(float x) { return 1.0f / (1.0f + __expf(-x)); }
__device__ __forceinline__ float tanh_fast(float x) {
    return 2.0f / (1.0f + __expf(-2.0f * x)) - 1.0f;
}

// ---------------------------------------------------------------------------
// Pack Wf,Wc,Wi,Wo ([256,256] fp32) into bf16 B-fragment-major layout for
// mfma_f32_16x16x32_bf16 (identical to R2/R5, verified):
//   flat o = (((g*8 + ks)*16 + jf)*64 + lane)*8 + e
//   k = ks*32 + (lane>>4)*8 + e ;  j = jf*16 + (lane&15) ;  B[k][j] = W_g[j][k]
// ---------------------------------------------------------------------------
__global__ void __launch_bounds__(256)
prep_w_kernel(const float* __restrict__ Wf, const float* __restrict__ Wc,
              const float* __restrict__ Wi, const float* __restrict__ Wo,
              short* __restrict__ Bp)
{
    int o    = blockIdx.x * 256 + threadIdx.x;   // 0 .. 262143
    int e    = o & 7;
    int lane = (o >> 3) & 63;
    int jf   = (o >> 9) & 15;
    int ks   = (o >> 13) & 7;
    int g    = (o >> 16) & 3;
    int k = ks * 32 + (lane >> 4) * 8 + e;
    int j = jf * 16 + (lane & 15);
    const float* W = (g == 0) ? Wf : (g == 1) ? Wc : (g == 2) ? Wi : Wo;
    Bp[o] = f2bf(W[j * 256 + k]);
}

// ---------------------------------------------------------------------------
// Main fused kernel. 4096 blocks x 512 threads (8 waves). Block handles
// 32 batch rows x one j-half (128 of 256 gate-cols) for all 4 gates.
// Wave w owns per-gate cols [jh*128 + w*16, +16) -> acc[4][2] = 32 VGPRs.
// One barrier per block. Cell/bias loaded per-lane before the barrier.
// ---------------------------------------------------------------------------
__global__ void __launch_bounds__(512, 6)
lstm_fused(const float* __restrict__ inp, const float* __restrict__ hid,
           const float* __restrict__ cell, const short* __restrict__ Bp,
           const float* __restrict__ bfv, const float* __restrict__ bcv,
           const float* __restrict__ biv, const float* __restrict__ bov,
           float* __restrict__ out)
{
    __shared__ short As[TROWS * Hdim];      // 16 KB combine tile (swizzled)

    const int tid  = threadIdx.x;
    const int lane = tid & 63;
    const int wave = tid >> 6;              // 0..7
    const int lm   = lane & 15;
    const int lk   = lane >> 4;

    // XCD-paired swizzle: bids 16t+k and 16t+8+k (same XCD under %8
    // round-robin) are the two j-halves of the same row-tile.
    const int bid     = blockIdx.x;
    const int rowtile = (bid >> 4) * 8 + (bid & 7);
    const int jh      = (bid >> 3) & 1;
    const int rowblk  = rowtile * TROWS;

    // ---- stage combine = input + hidden (bf16) into LDS -------------------
    // 1024 chunks of 8 elems; 512 threads -> 2 chunks each.
#pragma unroll
    for (int c = 0; c < 2; ++c) {
        int cc  = tid + c * 512;         // chunk 0..1023
        int row = cc >> 5;               // 0..31
        int k0  = (cc & 31) * 8;         // 0..248
        const float4* ip = reinterpret_cast<const float4*>(inp + (size_t)(rowblk + row) * Hdim + k0);
        const float4* hp = reinterpret_cast<const float4*>(hid + (size_t)(rowblk + row) * Hdim + k0);
        float4 a0 = ip[0], a1 = ip[1];
        float4 h0 = hp[0], h1 = hp[1];
        short8 v;
        v[0] = f2bf(a0.x + h0.x);
        v[1] = f2bf(a0.y + h0.y);
        v[2] = f2bf(a0.z + h0.z);
        v[3] = f2bf(a0.w + h0.w);
        v[4] = f2bf(a1.x + h1.x);
        v[5] = f2bf(a1.y + h1.y);
        v[6] = f2bf(a1.z + h1.z);
        v[7] = f2bf(a1.w + h1.w);
        int byte = row * 512 + k0 * 2;
        byte ^= (row & 7) << 4;          // bank-conflict swizzle
        *reinterpret_cast<short8*>(reinterpret_cast<char*>(As) + byte) = v;
    }

    // ---- per-lane early loads: bias (4) + cell (8); latency drains with
    //      the staging barrier, off the epilogue critical path --------------
    const int j = jh * 128 + wave * 16 + lm;   // this lane's gate-col
    float bF = bfv[j], bC = bcv[j], bI = biv[j], bO = bov[j];
    float cv[2][4];
#pragma unroll
    for (int mf = 0; mf < 2; ++mf)
#pragma unroll
        for (int r = 0; r < 4; ++r)
            cv[mf][r] = cell[(size_t)(rowblk + mf * 16 + lk * 4 + r) * Hdim + j];

    __syncthreads();                     // As visible (all loads drained)

    // ---- acc init = bias (rows differ across regs, j fixed per lane) ------
    f32x4 acc[4][2];                     // [gate][mf(rows)] = 32 VGPRs
    acc[0][0] = (f32x4){bF, bF, bF, bF};  acc[0][1] = acc[0][0];
    acc[1][0] = (f32x4){bC, bC, bC, bC};  acc[1][1] = acc[1][0];
    acc[2][0] = (f32x4){bI, bI, bI, bI};  acc[2][1] = acc[2][0];
    acc[3][0] = (f32x4){bO, bO, bO, bO};  acc[3][1] = acc[3][0];

    // ---- GEMM: K=256 in 8 steps ------------------------------------------
    const char* A = reinterpret_cast<const char*>(As);
    const int jf_global = jh * 8 + wave;             // 0..15
#pragma unroll
    for (int ks = 0; ks < 8; ++ks) {
        short8 cf[2];
#pragma unroll
        for (int mf = 0; mf < 2; ++mf) {
            int row  = mf * 16 + lm;
            int byte = row * 512 + (ks * 32 + lk * 8) * 2;
            byte ^= (row & 7) << 4;
            cf[mf] = *reinterpret_cast<const short8*>(A + byte);
        }
#pragma unroll
        for (int g = 0; g < 4; ++g) {
            int chunk = (g * 8 + ks) * 16 + jf_global;
            short8 b = *reinterpret_cast<const short8*>(
                           Bp + ((size_t)chunk * 64 + lane) * 8);
            acc[g][0] = __builtin_amdgcn_mfma_f32_16x16x32_bf16(cf[0], b, acc[g][0], 0, 0, 0);
            acc[g][1] = __builtin_amdgcn_mfma_f32_16x16x32_bf16(cf[1], b, acc[g][1], 0, 0, 0);
        }
    }

    // ---- epilogue: gates + cell/hidden state, scalar fp32 stores ----------
    float* out0 = out;                               // out gate
    float* out1 = out + (size_t)Bsz * Hdim;          // hidden_state
    float* out2 = out + (size_t)2 * Bsz * Hdim;      // cell_state

#pragma unroll
    for (int mf = 0; mf < 2; ++mf) {
#pragma unroll
        for (int r = 0; r < 4; ++r) {
            int row = rowblk + mf * 16 + lk * 4 + r;   // C/D: row=(lane>>4)*4+reg
            size_t off = (size_t)row * Hdim + j;
            float F = sigm(acc[0][mf][r]);
            float C = tanh_fast(acc[1][mf][r]);
            float I = sigm(sigm(acc[2][mf][r]));       // double sigmoid, per ref
            float O = sigm(acc[3][mf][r]);
            float cs = cv[mf][r] * F + C * I;
            float hs = O * tanh_fast(cs);
            out0[off] = O;
            out1[off] = hs;
            out2[off] = cs;
        }
    }
}

extern "C" void kernel_launch(void* const* d_in, const int* in_sizes, int n_in,
                              void* d_out, int out_size, void* d_ws, size_t ws_size,
                              hipStream_t stream)
{
    const float* inp  = (const float*)d_in[0];
    const float* hid  = (const float*)d_in[1];
    const float* cell = (const float*)d_in[2];
    const float* Wf   = (const float*)d_in[3];
    const float* bf_  = (const float*)d_in[4];
    const float* Wc   = (const float*)d_in[5];
    const float* bc_  = (const float*)d_in[6];
    const float* Wi   = (const float*)d_in[7];
    const float* bi_  = (const float*)d_in[8];
    const float* Wo   = (const float*)d_in[9];
    const float* bo_  = (const float*)d_in[10];

    short* Bp = (short*)d_ws;    // 512 KB packed bf16 weights

    prep_w_kernel<<<1024, 256, 0, stream>>>(Wf, Wc, Wi, Wo, Bp);
    lstm_fused<<<NBLK, 512, 0, stream>>>(inp, hid, cell, Bp,
                                         bf_, bc_, bi_, bo_, (float*)d_out);
}